// Round 7
// baseline (225.974 us; speedup 1.0000x reference)
//
#include <hip/hip_runtime.h>
#include <hip/hip_bf16.h>

#define NN 8192
#define D_IN 128
#define D_OUT 64
#define GAT_ALPHA 0.2f
#define LOG2E 1.4426950408889634f

typedef __attribute__((ext_vector_type(4))) float f32x4;
typedef __attribute__((ext_vector_type(8))) short short8;
typedef __attribute__((ext_vector_type(4))) int i32x4;

static __device__ __forceinline__ unsigned short f32_bf16(float f) {
    unsigned u = __builtin_bit_cast(unsigned, f);
    u += 0x7fffu + ((u >> 16) & 1u);   // round-to-nearest-even
    return (unsigned short)(u >> 16);
}

// ---- Kernel 1: wh = h@w; wh1p/wh2p (x log2e); whB = K-blocked bf16 wh^T ----
// whB[j>>3][dim][j&7]: element (dim, j) at whB[(j>>3)*512 + dim*8 + (j&7)]
__global__ __launch_bounds__(256) void gat_prep(
    const float* __restrict__ h, const float* __restrict__ w,
    const float* __restrict__ a,
    unsigned short* __restrict__ whB, float* __restrict__ wh1p,
    float* __restrict__ wh2p)
{
    __shared__ float hs[16 * 128];
    __shared__ float whs[16][64];
    const int t = threadIdx.x;
    const int i0 = blockIdx.x * 16;

    const float* hsrc = h + (size_t)i0 * D_IN;
    *(float4*)(hs + t * 8)     = *(const float4*)(hsrc + t * 8);
    *(float4*)(hs + t * 8 + 4) = *(const float4*)(hsrc + t * 8 + 4);
    __syncthreads();

    const int r  = t >> 4;          // local row 0..15
    const int og = (t & 15) * 4;    // 4 output dims
    f32x4 acc = {0.f, 0.f, 0.f, 0.f};
    for (int k = 0; k < D_IN; ++k) {
        float hv = hs[r * 128 + k];
        float4 wv = *(const float4*)(w + k * D_OUT + og);
        acc[0] += hv * wv.x; acc[1] += hv * wv.y;
        acc[2] += hv * wv.z; acc[3] += hv * wv.w;
    }
    whs[r][og]     = acc[0];
    whs[r][og + 1] = acc[1];
    whs[r][og + 2] = acc[2];
    whs[r][og + 3] = acc[3];

    float p1 = acc[0]*a[og] + acc[1]*a[og+1] + acc[2]*a[og+2] + acc[3]*a[og+3];
    float p2 = acc[0]*a[64+og] + acc[1]*a[64+og+1] + acc[2]*a[64+og+2] + acc[3]*a[64+og+3];
    #pragma unroll
    for (int m = 1; m < 16; m <<= 1) {
        p1 += __shfl_xor(p1, m);
        p2 += __shfl_xor(p2, m);
    }
    if ((t & 15) == 0) {
        wh1p[i0 + r] = p1 * LOG2E;
        wh2p[i0 + r] = p2 * LOG2E;
    }
    __syncthreads();

    {
        const int half = t >> 7;         // which 8-row group
        const int dim  = (t >> 1) & 63;
        const int e0   = (t & 1) * 4;
        ushort4 v;
        v.x = f32_bf16(whs[half * 8 + e0 + 0][dim]);
        v.y = f32_bf16(whs[half * 8 + e0 + 1][dim]);
        v.z = f32_bf16(whs[half * 8 + e0 + 2][dim]);
        v.w = f32_bf16(whs[half * 8 + e0 + 3][dim]);
        *(ushort4*)(whB + (size_t)(i0 / 8 + half) * 512 + dim * 8 + e0) = v;
    }
}

static __device__ __forceinline__ short8 pack8_bf16(const float* p) {
    union { unsigned int u[4]; short8 s; } r;
    asm("v_cvt_pk_bf16_f32 %0, %1, %2" : "=v"(r.u[0]) : "v"(p[0]), "v"(p[1]));
    asm("v_cvt_pk_bf16_f32 %0, %1, %2" : "=v"(r.u[1]) : "v"(p[2]), "v"(p[3]));
    asm("v_cvt_pk_bf16_f32 %0, %1, %2" : "=v"(r.u[2]) : "v"(p[4]), "v"(p[5]));
    asm("v_cvt_pk_bf16_f32 %0, %1, %2" : "=v"(r.u[3]) : "v"(p[6]), "v"(p[7]));
    return r.s;
}

// ---- Kernel 2 (fused): stream 16 adj rows (512 KB contiguous, nontemporal)
// -> bit masks in LDS -> fused softmax + att@wh + bias + elu.
// 512 blocks x 512 thr (8 waves, 2 blocks/CU). Wave wv: stages rows
// {2wv, 2wv+1}; computes cols [wv*1024,(wv+1)*1024) over all 16 rows.
__global__ __launch_bounds__(512) void gat_fused(
    const int* __restrict__ adj, const unsigned short* __restrict__ whB,
    const float* __restrict__ wh1p, const float* __restrict__ wh2p,
    const float* __restrict__ bias, float* __restrict__ out)
{
    __shared__ alignas(16) char smem[33792];
    unsigned int (*bmlds)[260] = (unsigned int(*)[260])smem;   // [16][260] = 16.6 KB
    float (*nums)[16][64] = (float(*)[16][64])smem;            // [8][16][64] = 32 KB
    float (*dens)[16] = (float(*)[16])(smem + 32768);          // [8][16]

    const int t    = threadIdx.x;
    const int wv   = t >> 6;
    const int lane = t & 63;
    const int il   = lane & 15;
    const int kg   = lane >> 4;
    const int r0   = blockIdx.x * 16;

    // ---- phase 1: stream adj rows -> 1-bit masks in LDS ----
    // 8 passes: s -> (row = 2wv + (s>>2), p = s&3); lane packs 32 ints (128 B)
    // into one mask dword bmlds[row][p*64+lane].
    for (int s = 0; s < 8; ++s) {
        const int row = wv * 2 + (s >> 2);
        const int p   = s & 3;
        const i32x4* q = (const i32x4*)(adj + (size_t)(r0 + row) * NN) + p * 512 + lane * 8;
        i32x4 v[8];
        #pragma unroll
        for (int k = 0; k < 8; ++k) v[k] = __builtin_nontemporal_load(q + k);
        unsigned m = 0;
        #pragma unroll
        for (int k = 0; k < 8; ++k) {
            m |= (unsigned)(v[k].x > 0) << (4 * k);
            m |= (unsigned)(v[k].y > 0) << (4 * k + 1);
            m |= (unsigned)(v[k].z > 0) << (4 * k + 2);
            m |= (unsigned)(v[k].w > 0) << (4 * k + 3);
        }
        bmlds[row][p * 64 + lane] = m;
    }
    __syncthreads();

    // ---- phase 2: compute (no barriers; masks from LDS, whB from L2) ----
    const float c = wh1p[r0 + il];
    const int shk = kg * 8;

    f32x4 acc0 = {0,0,0,0}, acc1 = {0,0,0,0}, acc2 = {0,0,0,0}, acc3 = {0,0,0,0};
    float den = 0.f;

    #pragma unroll 4
    for (int n = 0; n < 32; ++n) {
        const int jd = wv * 32 + n;      // dword (32-col) index
        const int j0 = jd * 32;          // global col

        unsigned int m0 = bmlds[il][jd] >> shk;
        float4 W0 = *(const float4*)(wh2p + j0 + kg * 8);
        float4 W1 = *(const float4*)(wh2p + j0 + kg * 8 + 4);

        const unsigned short* bb = whB + (size_t)(j0 / 8 + kg) * 512 + il * 8;
        short8 b0 = *(const short8*)(bb);
        short8 b1 = *(const short8*)(bb + 128);
        short8 b2 = *(const short8*)(bb + 256);
        short8 b3 = *(const short8*)(bb + 384);

        float wvv[8] = {W0.x, W0.y, W0.z, W0.w, W1.x, W1.y, W1.z, W1.w};
        float p0[8];
        #pragma unroll
        for (int e = 0; e < 8; ++e) {
            float x = c + wvv[e];
            x = fmaxf(x, GAT_ALPHA * x);
            float p = __builtin_amdgcn_exp2f(x);
            p = (m0 & (1u << e)) ? p : 0.f;
            den += p; p0[e] = p;
        }
        short8 af = pack8_bf16(p0);

        acc0 = __builtin_amdgcn_mfma_f32_16x16x32_bf16(af, b0, acc0, 0, 0, 0);
        acc1 = __builtin_amdgcn_mfma_f32_16x16x32_bf16(af, b1, acc1, 0, 0, 0);
        acc2 = __builtin_amdgcn_mfma_f32_16x16x32_bf16(af, b2, acc2, 0, 0, 0);
        acc3 = __builtin_amdgcn_mfma_f32_16x16x32_bf16(af, b3, acc3, 0, 0, 0);
    }

    // reduce den over kg (lanes il, il+16, il+32, il+48)
    den += __shfl_xor(den, 16);
    den += __shfl_xor(den, 32);

    __syncthreads();   // all bmlds reads done; safe to overlay smem

    if (kg == 0) dens[wv][il] = den;
    #pragma unroll
    for (int q = 0; q < 4; ++q) {
        nums[wv][kg * 4 + q][0 * 16 + il] = acc0[q];
        nums[wv][kg * 4 + q][1 * 16 + il] = acc1[q];
        nums[wv][kg * 4 + q][2 * 16 + il] = acc2[q];
        nums[wv][kg * 4 + q][3 * 16 + il] = acc3[q];
    }
    __syncthreads();

    #pragma unroll
    for (int k = 0; k < 2; ++k) {
        const int idx = k * 512 + t;
        const int rr = idx >> 6, cc = idx & 63;
        float s = 0.f, dd = 0.f;
        #pragma unroll
        for (int w8 = 0; w8 < 8; ++w8) { s += nums[w8][rr][cc]; dd += dens[w8][rr]; }
        float val = s / dd + bias[cc];
        out[(size_t)(r0 + rr) * D_OUT + cc] =
            val > 0.f ? val : (__builtin_amdgcn_exp2f(val * LOG2E) - 1.f);
    }
}

extern "C" void kernel_launch(void* const* d_in, const int* in_sizes, int n_in,
                              void* d_out, int out_size, void* d_ws, size_t ws_size,
                              hipStream_t stream) {
    const float* h   = (const float*)d_in[0];
    const int*   adj = (const int*)d_in[1];
    const float* w   = (const float*)d_in[2];
    const float* a   = (const float*)d_in[3];
    const float* b   = (const float*)d_in[4];
    float* out = (float*)d_out;

    char* ws = (char*)d_ws;
    unsigned short* whB = (unsigned short*)ws;                        // 1 MB
    float* wh1p = (float*)(ws + (size_t)D_OUT * NN * 2);              // 32 KB
    float* wh2p = (float*)(ws + (size_t)D_OUT * NN * 2 + NN * 4);     // 32 KB

    gat_prep<<<NN / 16, 256, 0, stream>>>(h, w, a, whB, wh1p, wh2p);
    gat_fused<<<NN / 16, 512, 0, stream>>>(adj, whB, wh1p, wh2p, b, out);
}

// Round 8
// 149.618 us; speedup vs baseline: 1.5103x; 1.5103x over previous
//
#include <hip/hip_runtime.h>
#include <hip/hip_bf16.h>

#define NN 8192
#define D_IN 128
#define D_OUT 64
#define GAT_ALPHA 0.2f
#define LOG2E 1.4426950408889634f

typedef __attribute__((ext_vector_type(4))) float f32x4;
typedef __attribute__((ext_vector_type(8))) short short8;

static __device__ __forceinline__ unsigned short f32_bf16(float f) {
    unsigned u = __builtin_bit_cast(unsigned, f);
    u += 0x7fffu + ((u >> 16) & 1u);   // round-to-nearest-even
    return (unsigned short)(u >> 16);
}

// ---- Kernel 1: wh = h@w; wh1p/wh2p (x log2e); whB = K-blocked bf16 wh^T ----
// whB[j>>3][dim][j&7]: element (dim, j) at whB[(j>>3)*512 + dim*8 + (j&7)]
__global__ __launch_bounds__(256) void gat_prep(
    const float* __restrict__ h, const float* __restrict__ w,
    const float* __restrict__ a,
    unsigned short* __restrict__ whB, float* __restrict__ wh1p,
    float* __restrict__ wh2p)
{
    __shared__ float hs[16 * 128];
    __shared__ float whs[16][64];
    const int t = threadIdx.x;
    const int i0 = blockIdx.x * 16;

    const float* hsrc = h + (size_t)i0 * D_IN;
    *(float4*)(hs + t * 8)     = *(const float4*)(hsrc + t * 8);
    *(float4*)(hs + t * 8 + 4) = *(const float4*)(hsrc + t * 8 + 4);
    __syncthreads();

    const int r  = t >> 4;          // local row 0..15
    const int og = (t & 15) * 4;    // 4 output dims
    f32x4 acc = {0.f, 0.f, 0.f, 0.f};
    for (int k = 0; k < D_IN; ++k) {
        float hv = hs[r * 128 + k];
        float4 wv = *(const float4*)(w + k * D_OUT + og);
        acc[0] += hv * wv.x; acc[1] += hv * wv.y;
        acc[2] += hv * wv.z; acc[3] += hv * wv.w;
    }
    whs[r][og]     = acc[0];
    whs[r][og + 1] = acc[1];
    whs[r][og + 2] = acc[2];
    whs[r][og + 3] = acc[3];

    float p1 = acc[0]*a[og] + acc[1]*a[og+1] + acc[2]*a[og+2] + acc[3]*a[og+3];
    float p2 = acc[0]*a[64+og] + acc[1]*a[64+og+1] + acc[2]*a[64+og+2] + acc[3]*a[64+og+3];
    #pragma unroll
    for (int m = 1; m < 16; m <<= 1) {
        p1 += __shfl_xor(p1, m);
        p2 += __shfl_xor(p2, m);
    }
    if ((t & 15) == 0) {
        wh1p[i0 + r] = p1 * LOG2E;
        wh2p[i0 + r] = p2 * LOG2E;
    }
    __syncthreads();

    {
        const int half = t >> 7;         // which 8-row group
        const int dim  = (t >> 1) & 63;
        const int e0   = (t & 1) * 4;
        ushort4 v;
        v.x = f32_bf16(whs[half * 8 + e0 + 0][dim]);
        v.y = f32_bf16(whs[half * 8 + e0 + 1][dim]);
        v.z = f32_bf16(whs[half * 8 + e0 + 2][dim]);
        v.w = f32_bf16(whs[half * 8 + e0 + 3][dim]);
        *(ushort4*)(whB + (size_t)(i0 / 8 + half) * 512 + dim * 8 + e0) = v;
    }
}

static __device__ __forceinline__ short8 pack8_bf16(const float* p) {
    union { unsigned int u[4]; short8 s; } r;
    asm("v_cvt_pk_bf16_f32 %0, %1, %2" : "=v"(r.u[0]) : "v"(p[0]), "v"(p[1]));
    asm("v_cvt_pk_bf16_f32 %0, %1, %2" : "=v"(r.u[1]) : "v"(p[2]), "v"(p[3]));
    asm("v_cvt_pk_bf16_f32 %0, %1, %2" : "=v"(r.u[2]) : "v"(p[4]), "v"(p[5]));
    asm("v_cvt_pk_bf16_f32 %0, %1, %2" : "=v"(r.u[3]) : "v"(p[6]), "v"(p[7]));
    return r.s;
}

// ---- Kernel 2 (fused): ballot-pack 16 adj rows (perfectly coalesced scalar
// loads, 64 consecutive ints/instr) -> bit masks in LDS -> fused softmax +
// att@wh + bias + elu. 512 blocks x 512 thr (8 waves, 2 blocks/CU).
// Wave wv: packs rows {2wv, 2wv+1}; computes cols [wv*1024,(wv+1)*1024).
__global__ __launch_bounds__(512) void gat_fused(
    const int* __restrict__ adj, const unsigned short* __restrict__ whB,
    const float* __restrict__ wh1p, const float* __restrict__ wh2p,
    const float* __restrict__ bias, float* __restrict__ out)
{
    __shared__ alignas(16) char smem[33792];
    unsigned int (*bmlds)[260] = (unsigned int(*)[260])smem;   // [16][260] = 16.6 KB
    float (*nums)[16][64] = (float(*)[16][64])smem;            // [8][16][64] = 32 KB
    float (*dens)[16] = (float(*)[16])(smem + 32768);          // [8][16]

    const int t    = threadIdx.x;
    const int wv   = t >> 6;
    const int lane = t & 63;
    const int il   = lane & 15;
    const int kg   = lane >> 4;
    const int r0   = blockIdx.x * 16;

    // ---- phase 1: ballot-pack adj rows -> 1-bit masks in LDS ----
    // wave handles rows 2wv, 2wv+1; per chunk: 64 consecutive ints, one ballot.
    #pragma unroll 2
    for (int rr = 0; rr < 2; ++rr) {
        const int row = wv * 2 + rr;
        const int* src = adj + (size_t)(r0 + row) * NN + lane;
        #pragma unroll 8
        for (int ch = 0; ch < 128; ++ch) {
            int v = src[ch * 64];
            unsigned long long m = __ballot(v > 0);
            if (lane == 0)
                *(unsigned long long*)&bmlds[row][2 * ch] = m;
        }
    }
    __syncthreads();

    // ---- phase 2: compute (no barriers; masks from LDS, whB from L2) ----
    const float c = wh1p[r0 + il];
    const int shk = kg * 8;

    f32x4 acc0 = {0,0,0,0}, acc1 = {0,0,0,0}, acc2 = {0,0,0,0}, acc3 = {0,0,0,0};
    float den = 0.f;

    #pragma unroll 4
    for (int n = 0; n < 32; ++n) {
        const int jd = wv * 32 + n;      // dword (32-col) index
        const int j0 = jd * 32;          // global col

        unsigned int m0 = bmlds[il][jd] >> shk;
        float4 W0 = *(const float4*)(wh2p + j0 + kg * 8);
        float4 W1 = *(const float4*)(wh2p + j0 + kg * 8 + 4);

        const unsigned short* bb = whB + (size_t)(j0 / 8 + kg) * 512 + il * 8;
        short8 b0 = *(const short8*)(bb);
        short8 b1 = *(const short8*)(bb + 128);
        short8 b2 = *(const short8*)(bb + 256);
        short8 b3 = *(const short8*)(bb + 384);

        float wvv[8] = {W0.x, W0.y, W0.z, W0.w, W1.x, W1.y, W1.z, W1.w};
        float p0[8];
        #pragma unroll
        for (int e = 0; e < 8; ++e) {
            float x = c + wvv[e];
            x = fmaxf(x, GAT_ALPHA * x);
            float p = __builtin_amdgcn_exp2f(x);
            p = (m0 & (1u << e)) ? p : 0.f;
            den += p; p0[e] = p;
        }
        short8 af = pack8_bf16(p0);

        acc0 = __builtin_amdgcn_mfma_f32_16x16x32_bf16(af, b0, acc0, 0, 0, 0);
        acc1 = __builtin_amdgcn_mfma_f32_16x16x32_bf16(af, b1, acc1, 0, 0, 0);
        acc2 = __builtin_amdgcn_mfma_f32_16x16x32_bf16(af, b2, acc2, 0, 0, 0);
        acc3 = __builtin_amdgcn_mfma_f32_16x16x32_bf16(af, b3, acc3, 0, 0, 0);
    }

    // reduce den over kg (lanes il, il+16, il+32, il+48)
    den += __shfl_xor(den, 16);
    den += __shfl_xor(den, 32);

    __syncthreads();   // all bmlds reads done; safe to overlay smem

    if (kg == 0) dens[wv][il] = den;
    #pragma unroll
    for (int q = 0; q < 4; ++q) {
        nums[wv][kg * 4 + q][0 * 16 + il] = acc0[q];
        nums[wv][kg * 4 + q][1 * 16 + il] = acc1[q];
        nums[wv][kg * 4 + q][2 * 16 + il] = acc2[q];
        nums[wv][kg * 4 + q][3 * 16 + il] = acc3[q];
    }
    __syncthreads();

    #pragma unroll
    for (int k = 0; k < 2; ++k) {
        const int idx = k * 512 + t;
        const int rr = idx >> 6, cc = idx & 63;
        float s = 0.f, dd = 0.f;
        #pragma unroll
        for (int w8 = 0; w8 < 8; ++w8) { s += nums[w8][rr][cc]; dd += dens[w8][rr]; }
        float val = s / dd + bias[cc];
        out[(size_t)(r0 + rr) * D_OUT + cc] =
            val > 0.f ? val : (__builtin_amdgcn_exp2f(val * LOG2E) - 1.f);
    }
}

extern "C" void kernel_launch(void* const* d_in, const int* in_sizes, int n_in,
                              void* d_out, int out_size, void* d_ws, size_t ws_size,
                              hipStream_t stream) {
    const float* h   = (const float*)d_in[0];
    const int*   adj = (const int*)d_in[1];
    const float* w   = (const float*)d_in[2];
    const float* a   = (const float*)d_in[3];
    const float* b   = (const float*)d_in[4];
    float* out = (float*)d_out;

    char* ws = (char*)d_ws;
    unsigned short* whB = (unsigned short*)ws;                        // 1 MB
    float* wh1p = (float*)(ws + (size_t)D_OUT * NN * 2);              // 32 KB
    float* wh2p = (float*)(ws + (size_t)D_OUT * NN * 2 + NN * 4);     // 32 KB

    gat_prep<<<NN / 16, 256, 0, stream>>>(h, w, a, whB, wh1p, wh2p);
    gat_fused<<<NN / 16, 512, 0, stream>>>(adj, whB, wh1p, wh2p, b, out);
}

// Round 9
// 85.442 us; speedup vs baseline: 2.6448x; 1.7511x over previous
//
#include <hip/hip_runtime.h>
#include <hip/hip_bf16.h>

#define NN 8192
#define D_IN 128
#define D_OUT 64
#define GAT_ALPHA 0.2f
#define LOG2E 1.4426950408889634f

typedef __attribute__((ext_vector_type(4))) float f32x4;
typedef __attribute__((ext_vector_type(8))) short short8;
typedef __attribute__((ext_vector_type(4))) int i32x4;

static __device__ __forceinline__ unsigned short f32_bf16(float f) {
    unsigned u = __builtin_bit_cast(unsigned, f);
    u += 0x7fffu + ((u >> 16) & 1u);   // round-to-nearest-even
    return (unsigned short)(u >> 16);
}

// ---- Kernel 1: wh = h@w; wh1p/wh2p (x log2e); whB = K-blocked bf16 wh^T ----
// whB[j>>3][dim][j&7]: element (dim, j) at whB[(j>>3)*512 + dim*8 + (j&7)]
__global__ __launch_bounds__(256) void gat_prep(
    const float* __restrict__ h, const float* __restrict__ w,
    const float* __restrict__ a,
    unsigned short* __restrict__ whB, float* __restrict__ wh1p,
    float* __restrict__ wh2p)
{
    __shared__ float hs[16 * 128];
    __shared__ float whs[16][64];
    const int t = threadIdx.x;
    const int i0 = blockIdx.x * 16;

    const float* hsrc = h + (size_t)i0 * D_IN;
    *(float4*)(hs + t * 8)     = *(const float4*)(hsrc + t * 8);
    *(float4*)(hs + t * 8 + 4) = *(const float4*)(hsrc + t * 8 + 4);
    __syncthreads();

    const int r  = t >> 4;          // local row 0..15
    const int og = (t & 15) * 4;    // 4 output dims
    f32x4 acc = {0.f, 0.f, 0.f, 0.f};
    for (int k = 0; k < D_IN; ++k) {
        float hv = hs[r * 128 + k];
        float4 wv = *(const float4*)(w + k * D_OUT + og);
        acc[0] += hv * wv.x; acc[1] += hv * wv.y;
        acc[2] += hv * wv.z; acc[3] += hv * wv.w;
    }
    whs[r][og]     = acc[0];
    whs[r][og + 1] = acc[1];
    whs[r][og + 2] = acc[2];
    whs[r][og + 3] = acc[3];

    float p1 = acc[0]*a[og] + acc[1]*a[og+1] + acc[2]*a[og+2] + acc[3]*a[og+3];
    float p2 = acc[0]*a[64+og] + acc[1]*a[64+og+1] + acc[2]*a[64+og+2] + acc[3]*a[64+og+3];
    #pragma unroll
    for (int m = 1; m < 16; m <<= 1) {
        p1 += __shfl_xor(p1, m);
        p2 += __shfl_xor(p2, m);
    }
    if ((t & 15) == 0) {
        wh1p[i0 + r] = p1 * LOG2E;
        wh2p[i0 + r] = p2 * LOG2E;
    }
    __syncthreads();

    {
        const int half = t >> 7;         // which 8-row group
        const int dim  = (t >> 1) & 63;
        const int e0   = (t & 1) * 4;
        ushort4 v;
        v.x = f32_bf16(whs[half * 8 + e0 + 0][dim]);
        v.y = f32_bf16(whs[half * 8 + e0 + 1][dim]);
        v.z = f32_bf16(whs[half * 8 + e0 + 2][dim]);
        v.w = f32_bf16(whs[half * 8 + e0 + 3][dim]);
        *(ushort4*)(whB + (size_t)(i0 / 8 + half) * 512 + dim * 8 + e0) = v;
    }
}

// ---- Kernel 2: pure streaming compress adj -> 1-bit mask (8 MB) ----
// 2048 blocks x 256 thr; grid-stride; lane reads 32 B (2 x int4), packs 1 byte.
// Branch-free, no cross-lane: loads pipeline freely (16 in flight at unroll 8).
__global__ __launch_bounds__(256) void gat_compress(
    const int* __restrict__ adj, unsigned char* __restrict__ bm)
{
    const int g = blockIdx.x * 256 + threadIdx.x;   // 524288 threads
    #pragma unroll 8
    for (int s = 0; s < 16; ++s) {
        const size_t B = (size_t)s * 524288 + g;    // output byte index
        const i32x4* p = (const i32x4*)(adj + B * 8);
        i32x4 v0 = p[0];
        i32x4 v1 = p[1];
        unsigned b =
            (unsigned)(v0.x > 0)        | ((unsigned)(v0.y > 0) << 1) |
            ((unsigned)(v0.z > 0) << 2) | ((unsigned)(v0.w > 0) << 3) |
            ((unsigned)(v1.x > 0) << 4) | ((unsigned)(v1.y > 0) << 5) |
            ((unsigned)(v1.z > 0) << 6) | ((unsigned)(v1.w > 0) << 7);
        bm[B] = (unsigned char)b;
    }
}

static __device__ __forceinline__ short8 pack8_bf16(const float* p) {
    union { unsigned int u[4]; short8 s; } r;
    asm("v_cvt_pk_bf16_f32 %0, %1, %2" : "=v"(r.u[0]) : "v"(p[0]), "v"(p[1]));
    asm("v_cvt_pk_bf16_f32 %0, %1, %2" : "=v"(r.u[1]) : "v"(p[2]), "v"(p[3]));
    asm("v_cvt_pk_bf16_f32 %0, %1, %2" : "=v"(r.u[2]) : "v"(p[4]), "v"(p[5]));
    asm("v_cvt_pk_bf16_f32 %0, %1, %2" : "=v"(r.u[3]) : "v"(p[6]), "v"(p[7]));
    return r.s;
}

// ---- Kernel 3: bitmask-driven fused softmax + att@wh + bias + elu ----
// 256 blocks x 512 thr (8 waves). Block owns 32 rows; wave wv owns cols
// [wv*1024,(wv+1)*1024) = 32 tiles of 32. Bitmask slice (32 KB) staged to LDS.
__global__ __launch_bounds__(512) void gat_main(
    const unsigned int* __restrict__ bm, const unsigned short* __restrict__ whB,
    const float* __restrict__ wh1p, const float* __restrict__ wh2p,
    const float* __restrict__ bias, float* __restrict__ out)
{
    __shared__ alignas(16) char smem[66560];
    unsigned int (*bmlds)[260] = (unsigned int(*)[260])smem;   // [32][260] = 33.3 KB
    float (*nums)[32][64] = (float(*)[32][64])smem;            // [8][32][64] = 64 KB (overlay)
    float (*dens)[32] = (float(*)[32])(smem + 65536);          // [8][32]

    const int t    = threadIdx.x;
    const int wv   = t >> 6;
    const int lane = t & 63;
    const int il   = lane & 15;
    const int kg   = lane >> 4;
    const int r0   = blockIdx.x * 32;

    // ---- stage 32 rows of bitmask (32 KB, fully coalesced uint4) ----
    {
        const uint4* src = (const uint4*)bm + (size_t)r0 * 64;   // 2048 uint4
        #pragma unroll
        for (int q = 0; q < 4; ++q) {
            const int k = q * 512 + t;
            uint4 v = src[k];
            const int rr = k >> 6, c4 = (k & 63) * 4;
            *(uint4*)&bmlds[rr][c4] = v;
        }
    }
    __syncthreads();

    // ---- compute (no barriers; masks from LDS, whB from L2) ----
    const float c0 = wh1p[r0 + il];
    const float c1 = wh1p[r0 + 16 + il];
    const int shk = kg * 8;

    f32x4 acc[2][4] = {};
    float den0 = 0.f, den1 = 0.f;

    #pragma unroll 4
    for (int n = 0; n < 32; ++n) {
        const int jd = wv * 32 + n;      // dword (32-col) index
        const int j0 = jd * 32;          // global col

        unsigned int m0 = bmlds[il][jd] >> shk;
        unsigned int m1 = bmlds[16 + il][jd] >> shk;
        float4 W0 = *(const float4*)(wh2p + j0 + kg * 8);
        float4 W1 = *(const float4*)(wh2p + j0 + kg * 8 + 4);

        const unsigned short* bb = whB + (size_t)(j0 / 8 + kg) * 512 + il * 8;
        short8 b0 = *(const short8*)(bb);
        short8 b1 = *(const short8*)(bb + 128);
        short8 b2 = *(const short8*)(bb + 256);
        short8 b3 = *(const short8*)(bb + 384);

        float wvv[8] = {W0.x, W0.y, W0.z, W0.w, W1.x, W1.y, W1.z, W1.w};
        float p0[8], p1v[8];
        #pragma unroll
        for (int e = 0; e < 8; ++e) {
            float x = c0 + wvv[e];
            x = fmaxf(x, GAT_ALPHA * x);
            float p = __builtin_amdgcn_exp2f(x);
            p = (m0 & (1u << e)) ? p : 0.f;
            den0 += p; p0[e] = p;
            float y = c1 + wvv[e];
            y = fmaxf(y, GAT_ALPHA * y);
            float q = __builtin_amdgcn_exp2f(y);
            q = (m1 & (1u << e)) ? q : 0.f;
            den1 += q; p1v[e] = q;
        }
        short8 af0 = pack8_bf16(p0);
        short8 af1 = pack8_bf16(p1v);

        acc[0][0] = __builtin_amdgcn_mfma_f32_16x16x32_bf16(af0, b0, acc[0][0], 0, 0, 0);
        acc[1][0] = __builtin_amdgcn_mfma_f32_16x16x32_bf16(af1, b0, acc[1][0], 0, 0, 0);
        acc[0][1] = __builtin_amdgcn_mfma_f32_16x16x32_bf16(af0, b1, acc[0][1], 0, 0, 0);
        acc[1][1] = __builtin_amdgcn_mfma_f32_16x16x32_bf16(af1, b1, acc[1][1], 0, 0, 0);
        acc[0][2] = __builtin_amdgcn_mfma_f32_16x16x32_bf16(af0, b2, acc[0][2], 0, 0, 0);
        acc[1][2] = __builtin_amdgcn_mfma_f32_16x16x32_bf16(af1, b2, acc[1][2], 0, 0, 0);
        acc[0][3] = __builtin_amdgcn_mfma_f32_16x16x32_bf16(af0, b3, acc[0][3], 0, 0, 0);
        acc[1][3] = __builtin_amdgcn_mfma_f32_16x16x32_bf16(af1, b3, acc[1][3], 0, 0, 0);
    }

    // reduce den over kg (lanes il, il+16, il+32, il+48)
    den0 += __shfl_xor(den0, 16); den0 += __shfl_xor(den0, 32);
    den1 += __shfl_xor(den1, 16); den1 += __shfl_xor(den1, 32);

    __syncthreads();   // all bmlds reads done; safe to overlay smem

    if (kg == 0) { dens[wv][il] = den0; dens[wv][16 + il] = den1; }
    #pragma unroll
    for (int q = 0; q < 4; ++q) {
        #pragma unroll
        for (int d = 0; d < 4; ++d) {
            nums[wv][kg * 4 + q][d * 16 + il]      = acc[0][d][q];
            nums[wv][16 + kg * 4 + q][d * 16 + il] = acc[1][d][q];
        }
    }
    __syncthreads();

    #pragma unroll
    for (int k = 0; k < 4; ++k) {
        const int idx = k * 512 + t;
        const int rr = idx >> 6, cc = idx & 63;
        float s = 0.f, dd = 0.f;
        #pragma unroll
        for (int w8 = 0; w8 < 8; ++w8) { s += nums[w8][rr][cc]; dd += dens[w8][rr]; }
        float val = s / dd + bias[cc];
        out[(size_t)(r0 + rr) * D_OUT + cc] =
            val > 0.f ? val : (__builtin_amdgcn_exp2f(val * LOG2E) - 1.f);
    }
}

extern "C" void kernel_launch(void* const* d_in, const int* in_sizes, int n_in,
                              void* d_out, int out_size, void* d_ws, size_t ws_size,
                              hipStream_t stream) {
    const float* h   = (const float*)d_in[0];
    const int*   adj = (const int*)d_in[1];
    const float* w   = (const float*)d_in[2];
    const float* a   = (const float*)d_in[3];
    const float* b   = (const float*)d_in[4];
    float* out = (float*)d_out;

    char* ws = (char*)d_ws;
    unsigned short* whB = (unsigned short*)ws;                        // 1 MB
    float* wh1p = (float*)(ws + (size_t)D_OUT * NN * 2);              // 32 KB
    float* wh2p = (float*)(ws + (size_t)D_OUT * NN * 2 + NN * 4);     // 32 KB
    unsigned char* bm = (unsigned char*)(ws + (size_t)D_OUT * NN * 2 + NN * 8); // 8 MB

    gat_prep<<<NN / 16, 256, 0, stream>>>(h, w, a, whB, wh1p, wh2p);
    gat_compress<<<2048, 256, 0, stream>>>(adj, bm);
    gat_main<<<NN / 32, 512, 0, stream>>>((const unsigned int*)bm, whB, wh1p, wh2p, b, out);
}

// Round 10
// 83.122 us; speedup vs baseline: 2.7186x; 1.0279x over previous
//
#include <hip/hip_runtime.h>
#include <hip/hip_bf16.h>

#define NN 8192
#define D_IN 128
#define D_OUT 64
#define GAT_ALPHA 0.2f
#define LOG2E 1.4426950408889634f

typedef __attribute__((ext_vector_type(4))) float f32x4;
typedef __attribute__((ext_vector_type(8))) short short8;
typedef __attribute__((ext_vector_type(4))) int i32x4;

static __device__ __forceinline__ unsigned short f32_bf16(float f) {
    unsigned u = __builtin_bit_cast(unsigned, f);
    u += 0x7fffu + ((u >> 16) & 1u);   // round-to-nearest-even
    return (unsigned short)(u >> 16);
}

// ---- Kernel 1: wh = h@w; wh1p/wh2p (x log2e); whB = K-blocked bf16 wh^T ----
// whB[j>>3][dim][j&7]: element (dim, j) at whB[(j>>3)*512 + dim*8 + (j&7)]
__global__ __launch_bounds__(256) void gat_prep(
    const float* __restrict__ h, const float* __restrict__ w,
    const float* __restrict__ a,
    unsigned short* __restrict__ whB, float* __restrict__ wh1p,
    float* __restrict__ wh2p)
{
    __shared__ float hs[16 * 128];
    __shared__ float whs[16][64];
    const int t = threadIdx.x;
    const int i0 = blockIdx.x * 16;

    const float* hsrc = h + (size_t)i0 * D_IN;
    *(float4*)(hs + t * 8)     = *(const float4*)(hsrc + t * 8);
    *(float4*)(hs + t * 8 + 4) = *(const float4*)(hsrc + t * 8 + 4);
    __syncthreads();

    const int r  = t >> 4;          // local row 0..15
    const int og = (t & 15) * 4;    // 4 output dims
    f32x4 acc = {0.f, 0.f, 0.f, 0.f};
    for (int k = 0; k < D_IN; ++k) {
        float hv = hs[r * 128 + k];
        float4 wv = *(const float4*)(w + k * D_OUT + og);
        acc[0] += hv * wv.x; acc[1] += hv * wv.y;
        acc[2] += hv * wv.z; acc[3] += hv * wv.w;
    }
    whs[r][og]     = acc[0];
    whs[r][og + 1] = acc[1];
    whs[r][og + 2] = acc[2];
    whs[r][og + 3] = acc[3];

    float p1 = acc[0]*a[og] + acc[1]*a[og+1] + acc[2]*a[og+2] + acc[3]*a[og+3];
    float p2 = acc[0]*a[64+og] + acc[1]*a[64+og+1] + acc[2]*a[64+og+2] + acc[3]*a[64+og+3];
    #pragma unroll
    for (int m = 1; m < 16; m <<= 1) {
        p1 += __shfl_xor(p1, m);
        p2 += __shfl_xor(p2, m);
    }
    if ((t & 15) == 0) {
        wh1p[i0 + r] = p1 * LOG2E;
        wh2p[i0 + r] = p2 * LOG2E;
    }
    __syncthreads();

    {
        const int half = t >> 7;         // which 8-row group
        const int dim  = (t >> 1) & 63;
        const int e0   = (t & 1) * 4;
        ushort4 v;
        v.x = f32_bf16(whs[half * 8 + e0 + 0][dim]);
        v.y = f32_bf16(whs[half * 8 + e0 + 1][dim]);
        v.z = f32_bf16(whs[half * 8 + e0 + 2][dim]);
        v.w = f32_bf16(whs[half * 8 + e0 + 3][dim]);
        *(ushort4*)(whB + (size_t)(i0 / 8 + half) * 512 + dim * 8 + e0) = v;
    }
}

static __device__ __forceinline__ short8 pack8_bf16(const float* p) {
    union { unsigned int u[4]; short8 s; } r;
    asm("v_cvt_pk_bf16_f32 %0, %1, %2" : "=v"(r.u[0]) : "v"(p[0]), "v"(p[1]));
    asm("v_cvt_pk_bf16_f32 %0, %1, %2" : "=v"(r.u[1]) : "v"(p[2]), "v"(p[3]));
    asm("v_cvt_pk_bf16_f32 %0, %1, %2" : "=v"(r.u[2]) : "v"(p[4]), "v"(p[5]));
    asm("v_cvt_pk_bf16_f32 %0, %1, %2" : "=v"(r.u[3]) : "v"(p[6]), "v"(p[7]));
    return r.s;
}

// ---- Kernel 2 (fused): NT-stream 16 adj rows (1 KB fully-consumed per load
// instr, L3-bypass) -> nibble pack + 1 shfl -> bit masks in LDS -> fused
// softmax + att@wh + bias + elu. 512 blocks x 512 thr (8 waves, 2 blocks/CU).
// Wave wv packs rows {2wv, 2wv+1}; computes cols [wv*1024,(wv+1)*1024).
__global__ __launch_bounds__(512) void gat_fused(
    const int* __restrict__ adj, const unsigned short* __restrict__ whB,
    const float* __restrict__ wh1p, const float* __restrict__ wh2p,
    const float* __restrict__ bias, float* __restrict__ out)
{
    __shared__ alignas(16) char smem[33792];
    unsigned int (*bmlds)[260] = (unsigned int(*)[260])smem;   // [16][260] = 16.6 KB
    float (*nums)[16][64] = (float(*)[16][64])smem;            // [8][16][64] = 32 KB (overlay)
    float (*dens)[16] = (float(*)[16])(smem + 32768);          // [8][16]

    const int t    = threadIdx.x;
    const int wv   = t >> 6;
    const int lane = t & 63;
    const int il   = lane & 15;
    const int kg   = lane >> 4;
    const int r0   = blockIdx.x * 16;

    // ---- phase 1: NT-stream rows -> 1-bit masks in LDS ----
    // instr k covers ints [k*256,(k+1)*256) of the row; lane gets 4 ints =
    // nibble for cols k*256+4*lane..+3. shfl_xor(1) merges byte pairs; even
    // lane writes byte g = k*32 + lane/2 of the row's mask.
    #pragma unroll 2
    for (int rr = 0; rr < 2; ++rr) {
        const int row = wv * 2 + rr;
        const int* src = adj + (size_t)(r0 + row) * NN;
        #pragma unroll
        for (int kb = 0; kb < 4; ++kb) {
            i32x4 v[8];
            #pragma unroll
            for (int k = 0; k < 8; ++k)
                v[k] = __builtin_nontemporal_load(
                    (const i32x4*)(src + (kb * 8 + k) * 256) + lane);
            #pragma unroll
            for (int k = 0; k < 8; ++k) {
                unsigned nib =
                    (unsigned)(v[k].x > 0)        | ((unsigned)(v[k].y > 0) << 1) |
                    ((unsigned)(v[k].z > 0) << 2) | ((unsigned)(v[k].w > 0) << 3);
                unsigned other = (unsigned)__shfl_xor((int)nib, 1);
                if (!(lane & 1)) {
                    ((unsigned char*)smem)[row * 1040 + (kb * 8 + k) * 32 + (lane >> 1)] =
                        (unsigned char)(nib | (other << 4));
                }
            }
        }
    }
    __syncthreads();

    // ---- phase 2: compute (no barriers; masks from LDS, whB from L2) ----
    const float c = wh1p[r0 + il];
    const int shk = kg * 8;

    f32x4 acc0 = {0,0,0,0}, acc1 = {0,0,0,0}, acc2 = {0,0,0,0}, acc3 = {0,0,0,0};
    float den = 0.f;

    #pragma unroll 4
    for (int n = 0; n < 32; ++n) {
        const int jd = wv * 32 + n;      // dword (32-col) index
        const int j0 = jd * 32;          // global col

        unsigned int m0 = bmlds[il][jd] >> shk;
        float4 W0 = *(const float4*)(wh2p + j0 + kg * 8);
        float4 W1 = *(const float4*)(wh2p + j0 + kg * 8 + 4);

        const unsigned short* bb = whB + (size_t)(j0 / 8 + kg) * 512 + il * 8;
        short8 b0 = *(const short8*)(bb);
        short8 b1 = *(const short8*)(bb + 128);
        short8 b2 = *(const short8*)(bb + 256);
        short8 b3 = *(const short8*)(bb + 384);

        float wvv[8] = {W0.x, W0.y, W0.z, W0.w, W1.x, W1.y, W1.z, W1.w};
        float p0[8];
        #pragma unroll
        for (int e = 0; e < 8; ++e) {
            float x = c + wvv[e];
            x = fmaxf(x, GAT_ALPHA * x);
            float p = __builtin_amdgcn_exp2f(x);
            p = (m0 & (1u << e)) ? p : 0.f;
            den += p; p0[e] = p;
        }
        short8 af = pack8_bf16(p0);

        acc0 = __builtin_amdgcn_mfma_f32_16x16x32_bf16(af, b0, acc0, 0, 0, 0);
        acc1 = __builtin_amdgcn_mfma_f32_16x16x32_bf16(af, b1, acc1, 0, 0, 0);
        acc2 = __builtin_amdgcn_mfma_f32_16x16x32_bf16(af, b2, acc2, 0, 0, 0);
        acc3 = __builtin_amdgcn_mfma_f32_16x16x32_bf16(af, b3, acc3, 0, 0, 0);
    }

    // reduce den over kg (lanes il, il+16, il+32, il+48)
    den += __shfl_xor(den, 16);
    den += __shfl_xor(den, 32);

    __syncthreads();   // all bmlds reads done; safe to overlay smem

    if (kg == 0) dens[wv][il] = den;
    #pragma unroll
    for (int q = 0; q < 4; ++q) {
        nums[wv][kg * 4 + q][0 * 16 + il] = acc0[q];
        nums[wv][kg * 4 + q][1 * 16 + il] = acc1[q];
        nums[wv][kg * 4 + q][2 * 16 + il] = acc2[q];
        nums[wv][kg * 4 + q][3 * 16 + il] = acc3[q];
    }
    __syncthreads();

    #pragma unroll
    for (int k = 0; k < 2; ++k) {
        const int idx = k * 512 + t;
        const int rr = idx >> 6, cc = idx & 63;
        float s = 0.f, dd = 0.f;
        #pragma unroll
        for (int w8 = 0; w8 < 8; ++w8) { s += nums[w8][rr][cc]; dd += dens[w8][rr]; }
        float val = s / dd + bias[cc];
        out[(size_t)(r0 + rr) * D_OUT + cc] =
            val > 0.f ? val : (__builtin_amdgcn_exp2f(val * LOG2E) - 1.f);
    }
}

extern "C" void kernel_launch(void* const* d_in, const int* in_sizes, int n_in,
                              void* d_out, int out_size, void* d_ws, size_t ws_size,
                              hipStream_t stream) {
    const float* h   = (const float*)d_in[0];
    const int*   adj = (const int*)d_in[1];
    const float* w   = (const float*)d_in[2];
    const float* a   = (const float*)d_in[3];
    const float* b   = (const float*)d_in[4];
    float* out = (float*)d_out;

    char* ws = (char*)d_ws;
    unsigned short* whB = (unsigned short*)ws;                        // 1 MB
    float* wh1p = (float*)(ws + (size_t)D_OUT * NN * 2);              // 32 KB
    float* wh2p = (float*)(ws + (size_t)D_OUT * NN * 2 + NN * 4);     // 32 KB

    gat_prep<<<NN / 16, 256, 0, stream>>>(h, w, a, whB, wh1p, wh2p);
    gat_fused<<<NN / 16, 512, 0, stream>>>(adj, whB, wh1p, wh2p, b, out);
}